// Round 1
// baseline (428.145 us; speedup 1.0000x reference)
//
#include <hip/hip_runtime.h>
#include <hip/hip_cooperative_groups.h>
#include <math.h>

namespace cg = cooperative_groups;

// Problem constants (MultiHeadCRA): B=8, C=1024, H=W=64
#define SDIM 4096      // spatial S = H*W
#define DDIM 128       // head_dim
#define RED 8          // reduced dim
#define BATCH 8
#define BH 64          // BATCH*HEADS
#define CH 1024        // channels per batch = HEADS*DDIM

// native 16B vector for nontemporal builtins
typedef float vfloat4 __attribute__((ext_vector_type(4)));

// workspace layout (floats):
//   avg partials [8 chunks][8192 rows] @ 0          (65536)
//   smax         [512 blocks]          @ 65536
//   ssum         [512 blocks]          @ 66048
//   --- fallback-only region ---
//   v            [BH*128]              @ 66560
//   attn         [BH*4096]             @ 74752
//   qr           [BH*8*4096]           @ 336896
#define WS_SMAX 65536
#define WS_SSUM 66048
#define WS_VV   66560
#define WS_ATT  74752
#define WS_QR   336896

__inline__ __device__ float wave_reduce_sum(float v) {
#pragma unroll
    for (int o = 32; o > 0; o >>= 1) v += __shfl_down(v, o, 64);
    return v;
}
__inline__ __device__ float wave_reduce_max(float v) {
#pragma unroll
    for (int o = 32; o > 0; o >>= 1) v = fmaxf(v, __shfl_down(v, o, 64));
    return v;
}

// ---------------------------------------------------------------------------
// Fused cooperative kernel. Grid: 64 bh x 8 s-chunks = 512 blocks (2/CU), 256 thr.
// Phase A: single pass over x: avg partials + 8 q-projections kept in registers.
// sync. Phase B: per-block head math (k, v), scores in-register, softmax partials.
// sync. Phase C: combine softmax, write out directly.
// ---------------------------------------------------------------------------
__global__ __launch_bounds__(256, 2) void k_fused(
        const float* __restrict__ x,
        const float* __restrict__ Wq, const float* __restrict__ bq,
        const float* __restrict__ Wk, const float* __restrict__ bk,
        const float* __restrict__ Wv, const float* __restrict__ bv,
        float* __restrict__ ws, float* __restrict__ out) {
    const int blk = blockIdx.x;
    const int bh = blk >> 3, chunk = blk & 7;
    const int h = bh & 7;
    const int t = threadIdx.x;
    const int wave = t >> 6, lane = t & 63;

    __shared__ float wqt[DDIM * RED];   // Wq transposed: [d][r]
    __shared__ float avgp[DDIM * 4];    // per-(d,wave) partial sums
    __shared__ float avgs[DDIM];
    __shared__ float kk[RED];
    __shared__ float bqs[RED];
    __shared__ float vvs[DDIM];
    __shared__ float attn[512];
    __shared__ float red4[4];
    __shared__ float gM, gInv;

    // stage Wq head slice transposed (per-d contiguous 8 floats -> 2x b128 bcast)
    for (int i = t; i < DDIM * RED; i += 256) {
        const int d = i >> 3, r = i & 7;
        wqt[i] = Wq[(h * RED + r) * DDIM + d];
    }
    __syncthreads();

    // ---- Phase A: one streaming pass over this block's x chunk ----
    const int s0 = chunk * 512 + t * 2;
    const float* xb = x + (size_t)bh * DDIM * SDIM + s0;
    float2 acc[RED];
#pragma unroll
    for (int r = 0; r < RED; ++r) acc[r] = make_float2(0.f, 0.f);

#pragma unroll 8
    for (int d = 0; d < DDIM; ++d) {
        const float2 xv = *(const float2*)(xb + (size_t)d * SDIM);
        const float4 wa = *(const float4*)&wqt[d * 8];
        const float4 wb = *(const float4*)&wqt[d * 8 + 4];
        acc[0].x += xv.x * wa.x; acc[0].y += xv.y * wa.x;
        acc[1].x += xv.x * wa.y; acc[1].y += xv.y * wa.y;
        acc[2].x += xv.x * wa.z; acc[2].y += xv.y * wa.z;
        acc[3].x += xv.x * wa.w; acc[3].y += xv.y * wa.w;
        acc[4].x += xv.x * wb.x; acc[4].y += xv.y * wb.x;
        acc[5].x += xv.x * wb.y; acc[5].y += xv.y * wb.y;
        acc[6].x += xv.x * wb.z; acc[6].y += xv.y * wb.z;
        acc[7].x += xv.x * wb.w; acc[7].y += xv.y * wb.w;
        float px = wave_reduce_sum(xv.x + xv.y);
        if (lane == 0) avgp[d * 4 + wave] = px;
    }
    __syncthreads();
    if (t < DDIM)
        ws[chunk * 8192 + bh * DDIM + t] =
            avgp[t * 4] + avgp[t * 4 + 1] + avgp[t * 4 + 2] + avgp[t * 4 + 3];

    cg::this_grid().sync();

    // ---- Phase B: head math + in-register scores + softmax partials ----
    if (t < DDIM) {
        float a = 0.f;
#pragma unroll
        for (int c = 0; c < 8; ++c) a += ws[c * 8192 + bh * DDIM + t];
        avgs[t] = a * (1.0f / SDIM);
    }
    __syncthreads();
    if (t < RED) {
        const float* wkr = Wk + (h * RED + t) * DDIM;
        float a = 0.f;
#pragma unroll 8
        for (int d = 0; d < DDIM; ++d) a += wkr[d] * avgs[d];
        kk[t] = a + bk[h * RED + t];
        bqs[t] = bq[h * RED + t];
    }
    if (t < DDIM) {
        const float* wvr = Wv + (h * DDIM + t) * DDIM;
        float a = 0.f;
#pragma unroll 8
        for (int d = 0; d < DDIM; ++d) a += wvr[d] * avgs[d];
        vvs[t] = a + bv[h * DDIM + t];
    }
    __syncthreads();

    float c0 = 0.f;
#pragma unroll
    for (int r = 0; r < RED; ++r) c0 += bqs[r] * kk[r];
    float2 sc = make_float2(c0, c0);
#pragma unroll
    for (int r = 0; r < RED; ++r) {
        sc.x += acc[r].x * kk[r];
        sc.y += acc[r].y * kk[r];
    }

    float m = wave_reduce_max(fmaxf(sc.x, sc.y));
    if (lane == 0) red4[wave] = m;
    __syncthreads();
    const float bm = fmaxf(fmaxf(red4[0], red4[1]), fmaxf(red4[2], red4[3]));
    float ps = expf(sc.x - bm) + expf(sc.y - bm);
    ps = wave_reduce_sum(ps);
    __syncthreads();                 // done reading red4 as maxes
    if (lane == 0) red4[wave] = ps;
    __syncthreads();
    if (t == 0) {
        ws[WS_SMAX + blk] = bm;
        ws[WS_SSUM + blk] = red4[0] + red4[1] + red4[2] + red4[3];
    }

    cg::this_grid().sync();

    // ---- Phase C: combine softmax across the 8 chunk-blocks, write out ----
    if (t == 0) {
        float pm[8];
        float M = -1e30f;
#pragma unroll
        for (int c = 0; c < 8; ++c) {
            pm[c] = ws[WS_SMAX + bh * 8 + c];
            M = fmaxf(M, pm[c]);
        }
        float S = 0.f;
#pragma unroll
        for (int c = 0; c < 8; ++c) S += ws[WS_SSUM + bh * 8 + c] * expf(pm[c] - M);
        gM = M;
        gInv = 1.0f / S;
    }
    __syncthreads();
    float2 a2;
    a2.x = expf(sc.x - gM) * gInv;
    a2.y = expf(sc.y - gM) * gInv;
    *(float2*)&attn[t * 2] = a2;
    __syncthreads();

    const vfloat4 a4 = ((const vfloat4*)attn)[t & 127];   // this thread's s4-slot
    float* ob = out + (size_t)bh * DDIM * SDIM + chunk * 512;
    const int ehalf = t >> 7;
#pragma unroll 8
    for (int i = 0; i < 64; ++i) {
        const int e = i * 2 + ehalf;
        vfloat4 o = a4 * vvs[e];
        __builtin_nontemporal_store(o, (vfloat4*)(ob + (size_t)e * SDIM) + (t & 127));
    }
}

// ---------------------------------------------------------------------------
// Fallback path (non-cooperative), used only if the coop launch is rejected.
// ---------------------------------------------------------------------------
__global__ __launch_bounds__(256, 2) void k_pass1(
        const float* __restrict__ x, const float* __restrict__ Wq,
        float* __restrict__ ws) {
    const int blk = blockIdx.x;
    const int bh = blk >> 3, chunk = blk & 7;
    const int h = bh & 7;
    const int t = threadIdx.x;
    const int wave = t >> 6, lane = t & 63;

    __shared__ float wqt[DDIM * RED];
    __shared__ float avgp[DDIM * 4];

    for (int i = t; i < DDIM * RED; i += 256) {
        const int d = i >> 3, r = i & 7;
        wqt[i] = Wq[(h * RED + r) * DDIM + d];
    }
    __syncthreads();

    const int s0 = chunk * 512 + t * 2;
    const float* xb = x + (size_t)bh * DDIM * SDIM + s0;
    float2 acc[RED];
#pragma unroll
    for (int r = 0; r < RED; ++r) acc[r] = make_float2(0.f, 0.f);

#pragma unroll 8
    for (int d = 0; d < DDIM; ++d) {
        const float2 xv = *(const float2*)(xb + (size_t)d * SDIM);
        const float4 wa = *(const float4*)&wqt[d * 8];
        const float4 wb = *(const float4*)&wqt[d * 8 + 4];
        acc[0].x += xv.x * wa.x; acc[0].y += xv.y * wa.x;
        acc[1].x += xv.x * wa.y; acc[1].y += xv.y * wa.y;
        acc[2].x += xv.x * wa.z; acc[2].y += xv.y * wa.z;
        acc[3].x += xv.x * wa.w; acc[3].y += xv.y * wa.w;
        acc[4].x += xv.x * wb.x; acc[4].y += xv.y * wb.x;
        acc[5].x += xv.x * wb.y; acc[5].y += xv.y * wb.y;
        acc[6].x += xv.x * wb.z; acc[6].y += xv.y * wb.z;
        acc[7].x += xv.x * wb.w; acc[7].y += xv.y * wb.w;
        float px = wave_reduce_sum(xv.x + xv.y);
        if (lane == 0) avgp[d * 4 + wave] = px;
    }
#pragma unroll
    for (int r = 0; r < RED; ++r)
        *(float2*)(ws + WS_QR + ((size_t)(bh * RED + r)) * SDIM + s0) = acc[r];
    __syncthreads();
    if (t < DDIM)
        ws[chunk * 8192 + bh * DDIM + t] =
            avgp[t * 4] + avgp[t * 4 + 1] + avgp[t * 4 + 2] + avgp[t * 4 + 3];
}

__global__ __launch_bounds__(256) void k_mid(
        const float* __restrict__ bq, const float* __restrict__ Wk,
        const float* __restrict__ bk, const float* __restrict__ Wv,
        const float* __restrict__ bv, float* __restrict__ ws) {
    const int bh = blockIdx.x;
    const int h = bh & 7;
    const int t = threadIdx.x;
    const int wave = t >> 6, lane = t & 63;

    __shared__ float avgs[DDIM], kk[RED], bqs[RED];
    __shared__ float smax[4], ssum[4];
    __shared__ float cc;

    if (t < DDIM) {
        float a = 0.f;
#pragma unroll
        for (int c = 0; c < 8; ++c) a += ws[c * 8192 + bh * DDIM + t];
        avgs[t] = a * (1.0f / SDIM);
    }
    __syncthreads();
    if (t < RED) {
        const float* wkr = Wk + (h * RED + t) * DDIM;
        float a = 0.f;
#pragma unroll 8
        for (int d = 0; d < DDIM; ++d) a += wkr[d] * avgs[d];
        kk[t] = a + bk[h * RED + t];
        bqs[t] = bq[h * RED + t];
    }
    if (t < DDIM) {
        const float* wvr = Wv + (h * DDIM + t) * DDIM;
        float a = 0.f;
#pragma unroll 8
        for (int d = 0; d < DDIM; ++d) a += wvr[d] * avgs[d];
        ws[WS_VV + bh * DDIM + t] = a + bv[h * DDIM + t];
    }
    __syncthreads();
    if (t == 0) {
        float a = 0.f;
#pragma unroll
        for (int r = 0; r < RED; ++r) a += bqs[r] * kk[r];
        cc = a;
    }
    __syncthreads();

    const float4* qr4 = (const float4*)(ws + WS_QR + (size_t)bh * RED * SDIM);
    float4 vals[4];
    float m = -1e30f;
#pragma unroll
    for (int p = 0; p < 4; ++p) {
        float4 a;
        a.x = cc; a.y = cc; a.z = cc; a.w = cc;
#pragma unroll
        for (int r = 0; r < RED; ++r) {
            const float4 q = qr4[r * 1024 + t + 256 * p];
            const float kr = kk[r];
            a.x += q.x * kr; a.y += q.y * kr; a.z += q.z * kr; a.w += q.w * kr;
        }
        vals[p] = a;
        m = fmaxf(m, fmaxf(fmaxf(a.x, a.y), fmaxf(a.z, a.w)));
    }
    m = wave_reduce_max(m);
    if (lane == 0) smax[wave] = m;
    __syncthreads();
    const float gm = fmaxf(fmaxf(smax[0], smax[1]), fmaxf(smax[2], smax[3]));
    float sum = 0.f;
#pragma unroll
    for (int p = 0; p < 4; ++p) {
        vals[p].x = expf(vals[p].x - gm);
        vals[p].y = expf(vals[p].y - gm);
        vals[p].z = expf(vals[p].z - gm);
        vals[p].w = expf(vals[p].w - gm);
        sum += vals[p].x + vals[p].y + vals[p].z + vals[p].w;
    }
    sum = wave_reduce_sum(sum);
    if (lane == 0) ssum[wave] = sum;
    __syncthreads();
    const float inv = 1.0f / (ssum[0] + ssum[1] + ssum[2] + ssum[3]);
    float4* att4 = (float4*)(ws + WS_ATT + (size_t)bh * SDIM);
#pragma unroll
    for (int p = 0; p < 4; ++p) {
        float4 o;
        o.x = vals[p].x * inv; o.y = vals[p].y * inv;
        o.z = vals[p].z * inv; o.w = vals[p].w * inv;
        att4[t + 256 * p] = o;
    }
}

__global__ __launch_bounds__(256) void k_bcast(const float* __restrict__ ws,
                                               float* __restrict__ out) {
    const vfloat4* attn = (const vfloat4*)(ws + WS_ATT);
    const float* vv = ws + WS_VV;
    const size_t total = (size_t)BATCH * CH * (SDIM / 4);
    const size_t stride = (size_t)gridDim.x * blockDim.x;
    for (size_t f = (size_t)blockIdx.x * blockDim.x + threadIdx.x; f < total; f += stride) {
        const int s4 = (int)(f & 1023);
        const int ce = (int)((f >> 10) & 1023);
        const int b = (int)(f >> 20);
        const int bh = (b << 3) | (ce >> 7);
        const int e = ce & 127;
        const vfloat4 a = attn[bh * 1024 + s4];
        const float vx = vv[bh * 128 + e];
        vfloat4 o = a * vx;
        __builtin_nontemporal_store(o, ((vfloat4*)out) + f);
    }
}

extern "C" void kernel_launch(void* const* d_in, const int* in_sizes, int n_in,
                              void* d_out, int out_size, void* d_ws, size_t ws_size,
                              hipStream_t stream) {
    const float* x  = (const float*)d_in[0];
    const float* Wq = (const float*)d_in[1];
    const float* bq = (const float*)d_in[2];
    const float* Wk = (const float*)d_in[3];
    const float* bk = (const float*)d_in[4];
    const float* Wv = (const float*)d_in[5];
    const float* bv = (const float*)d_in[6];
    float* out = (float*)d_out;
    float* ws  = (float*)d_ws;

    void* args[] = {(void*)&x, (void*)&Wq, (void*)&bq, (void*)&Wk, (void*)&bk,
                    (void*)&Wv, (void*)&bv, (void*)&ws, (void*)&out};
    hipError_t err = hipLaunchCooperativeKernel((const void*)k_fused, dim3(512),
                                                dim3(256), args, 0, stream);
    if (err != hipSuccess) {
        // non-cooperative fallback: same math, qr staged through workspace
        k_pass1<<<512, 256, 0, stream>>>(x, Wq, ws);
        k_mid<<<BH, 256, 0, stream>>>(bq, Wk, bk, Wv, bv, ws);
        k_bcast<<<8192, 256, 0, stream>>>(ws, out);
    }
}

// Round 2
// 409.704 us; speedup vs baseline: 1.0450x; 1.0450x over previous
//
#include <hip/hip_runtime.h>
#include <hip/hip_cooperative_groups.h>
#include <math.h>

namespace cg = cooperative_groups;

// Problem constants (MultiHeadCRA): B=8, C=1024, H=W=64
#define SDIM 4096      // spatial S = H*W
#define DDIM 128       // head_dim
#define RED 8          // reduced dim
#define BATCH 8
#define BH 64          // BATCH*HEADS
#define CH 1024        // channels per batch = HEADS*DDIM

// native 16B vector for nontemporal builtins
typedef float vfloat4 __attribute__((ext_vector_type(4)));

// workspace layout (floats):
//   avg partials [8 chunks][8192 rows] @ 0          (65536)
//   smax         [512 blocks]          @ 65536
//   ssum         [512 blocks]          @ 66048
//   --- fallback-only region ---
//   v            [BH*128]              @ 66560
//   attn         [BH*4096]             @ 74752
//   qr           [BH*8*4096]           @ 336896
#define WS_SMAX 65536
#define WS_SSUM 66048
#define WS_VV   66560
#define WS_ATT  74752
#define WS_QR   336896

__inline__ __device__ float wave_reduce_sum(float v) {
#pragma unroll
    for (int o = 32; o > 0; o >>= 1) v += __shfl_down(v, o, 64);
    return v;
}
__inline__ __device__ float wave_reduce_max(float v) {
#pragma unroll
    for (int o = 32; o > 0; o >>= 1) v = fmaxf(v, __shfl_down(v, o, 64));
    return v;
}

// ---------------------------------------------------------------------------
// Fused cooperative kernel. Grid: 64 bh x 8 s-chunks = 512 blocks (2/CU), 256 thr.
// Phase A: single streaming pass over x. Per thread: 8 q-projection accumulators
//   (registers). Avg row-sums via wave-local LDS transpose batched per 8 rows —
//   NO shuffles, NO barriers inside the loop (round-1's 242us was the per-d
//   shuffle chain serializing the stream).
// grid sync. Phase B: head math (k, v), scores from registers, softmax partials.
// grid sync. Phase C: combine softmax, write out directly.
// ---------------------------------------------------------------------------
__global__ __launch_bounds__(256, 2) void k_fused(
        const float* __restrict__ x,
        const float* __restrict__ Wq, const float* __restrict__ bq,
        const float* __restrict__ Wk, const float* __restrict__ bk,
        const float* __restrict__ Wv, const float* __restrict__ bv,
        float* __restrict__ ws, float* __restrict__ out) {
    const int blk = blockIdx.x;
    const int bh = blk >> 3, chunk = blk & 7;
    const int h = bh & 7;
    const int t = threadIdx.x;
    const int wave = t >> 6, lane = t & 63;

    __shared__ float wqt[DDIM * RED];       // Wq transposed: [d][r]
    __shared__ float sxy[4][8][65];         // per-wave column-sum staging (pad 65: bank-free)
    __shared__ float fpart[4][16][8][9];    // [wave][group][row][seg] partials (pad 9)
    __shared__ float avgs[DDIM];
    __shared__ float kk[RED];
    __shared__ float bqs[RED];
    __shared__ float vvs[DDIM];
    __shared__ float attnb[512];
    __shared__ float red4[4];
    __shared__ float gM, gInv;

    // stage Wq head slice transposed (per-d contiguous 8 floats -> 2x b128 bcast)
    for (int i = t; i < DDIM * RED; i += 256) {
        const int d = i >> 3, r = i & 7;
        wqt[i] = Wq[(h * RED + r) * DDIM + d];
    }
    __syncthreads();

    // ---- Phase A: one streaming pass over this block's x chunk ----
    const int s0 = chunk * 512 + t * 2;
    const float* xb = x + (size_t)bh * DDIM * SDIM + s0;
    float2 accq[RED];
#pragma unroll
    for (int r = 0; r < RED; ++r) accq[r] = make_float2(0.f, 0.f);

    const int r8 = lane >> 3;   // row (within 8-group) this lane reduces
    const int seg = lane & 7;   // 8-lane segment (16 columns) it covers

#pragma unroll 2
    for (int g = 0; g < 16; ++g) {
#pragma unroll
        for (int j = 0; j < 8; ++j) {
            const int d = g * 8 + j;
            const float2 xv = *(const float2*)(xb + (size_t)d * SDIM);
            const float4 wa = *(const float4*)&wqt[d * 8];
            const float4 wb = *(const float4*)&wqt[d * 8 + 4];
            accq[0].x += xv.x * wa.x; accq[0].y += xv.y * wa.x;
            accq[1].x += xv.x * wa.y; accq[1].y += xv.y * wa.y;
            accq[2].x += xv.x * wa.z; accq[2].y += xv.y * wa.z;
            accq[3].x += xv.x * wa.w; accq[3].y += xv.y * wa.w;
            accq[4].x += xv.x * wb.x; accq[4].y += xv.y * wb.x;
            accq[5].x += xv.x * wb.y; accq[5].y += xv.y * wb.y;
            accq[6].x += xv.x * wb.z; accq[6].y += xv.y * wb.z;
            accq[7].x += xv.x * wb.w; accq[7].y += xv.y * wb.w;
            sxy[wave][j][lane] = xv.x + xv.y;
        }
        // wave-local transpose-reduce: lane (r8,seg) sums 8 threads' entries of
        // row r8 (16 columns). Same-wave LDS ordering via lgkmcnt; no barrier.
        float ps = 0.f;
#pragma unroll
        for (int j = 0; j < 8; ++j) ps += sxy[wave][r8][seg * 8 + j];
        fpart[wave][g][r8][seg] = ps;
    }
    __syncthreads();
    if (t < DDIM) {
        // d = t: fold 4 waves x 8 segments
        float a = 0.f;
#pragma unroll
        for (int w = 0; w < 4; ++w)
#pragma unroll
            for (int s2 = 0; s2 < 8; ++s2)
                a += fpart[w][t >> 3][t & 7][s2];
        ws[chunk * 8192 + bh * DDIM + t] = a;
    }

    cg::this_grid().sync();

    // ---- Phase B: head math + in-register scores + softmax partials ----
    if (t < DDIM) {
        float a = 0.f;
#pragma unroll
        for (int c = 0; c < 8; ++c) a += ws[c * 8192 + bh * DDIM + t];
        avgs[t] = a * (1.0f / SDIM);
    }
    __syncthreads();
    if (t < RED) {
        const float* wkr = Wk + (h * RED + t) * DDIM;
        float a = 0.f;
#pragma unroll 8
        for (int d = 0; d < DDIM; ++d) a += wkr[d] * avgs[d];
        kk[t] = a + bk[h * RED + t];
        bqs[t] = bq[h * RED + t];
    }
    if (t < DDIM) {
        const float* wvr = Wv + (h * DDIM + t) * DDIM;
        float a = 0.f;
#pragma unroll 8
        for (int d = 0; d < DDIM; ++d) a += wvr[d] * avgs[d];
        vvs[t] = a + bv[h * DDIM + t];
    }
    __syncthreads();

    float c0 = 0.f;
#pragma unroll
    for (int r = 0; r < RED; ++r) c0 += bqs[r] * kk[r];
    float2 sc = make_float2(c0, c0);
#pragma unroll
    for (int r = 0; r < RED; ++r) {
        sc.x += accq[r].x * kk[r];
        sc.y += accq[r].y * kk[r];
    }

    float m = wave_reduce_max(fmaxf(sc.x, sc.y));
    if (lane == 0) red4[wave] = m;
    __syncthreads();
    const float bm = fmaxf(fmaxf(red4[0], red4[1]), fmaxf(red4[2], red4[3]));
    float ps2 = expf(sc.x - bm) + expf(sc.y - bm);
    ps2 = wave_reduce_sum(ps2);
    __syncthreads();                 // done reading red4 as maxes
    if (lane == 0) red4[wave] = ps2;
    __syncthreads();
    if (t == 0) {
        ws[WS_SMAX + blk] = bm;
        ws[WS_SSUM + blk] = red4[0] + red4[1] + red4[2] + red4[3];
    }

    cg::this_grid().sync();

    // ---- Phase C: combine softmax across the 8 chunk-blocks, write out ----
    if (t == 0) {
        float pm[8];
        float M = -1e30f;
#pragma unroll
        for (int c = 0; c < 8; ++c) {
            pm[c] = ws[WS_SMAX + bh * 8 + c];
            M = fmaxf(M, pm[c]);
        }
        float S = 0.f;
#pragma unroll
        for (int c = 0; c < 8; ++c) S += ws[WS_SSUM + bh * 8 + c] * expf(pm[c] - M);
        gM = M;
        gInv = 1.0f / S;
    }
    __syncthreads();
    float2 a2;
    a2.x = expf(sc.x - gM) * gInv;
    a2.y = expf(sc.y - gM) * gInv;
    *(float2*)&attnb[t * 2] = a2;
    __syncthreads();

    const vfloat4 a4 = ((const vfloat4*)attnb)[t & 127];   // this thread's s4-slot
    float* ob = out + (size_t)bh * DDIM * SDIM + chunk * 512;
    const int ehalf = t >> 7;
#pragma unroll 8
    for (int i = 0; i < 64; ++i) {
        const int e = i * 2 + ehalf;
        vfloat4 o = a4 * vvs[e];
        __builtin_nontemporal_store(o, (vfloat4*)(ob + (size_t)e * SDIM) + (t & 127));
    }
}

// ---------------------------------------------------------------------------
// Fallback path (non-cooperative), used only if the coop launch is rejected.
// ---------------------------------------------------------------------------
__global__ __launch_bounds__(256, 2) void k_pass1(
        const float* __restrict__ x, const float* __restrict__ Wq,
        float* __restrict__ ws) {
    const int blk = blockIdx.x;
    const int bh = blk >> 3, chunk = blk & 7;
    const int h = bh & 7;
    const int t = threadIdx.x;
    const int wave = t >> 6, lane = t & 63;

    __shared__ float wqt[DDIM * RED];
    __shared__ float sxy[4][8][65];
    __shared__ float fpart[4][16][8][9];

    for (int i = t; i < DDIM * RED; i += 256) {
        const int d = i >> 3, r = i & 7;
        wqt[i] = Wq[(h * RED + r) * DDIM + d];
    }
    __syncthreads();

    const int s0 = chunk * 512 + t * 2;
    const float* xb = x + (size_t)bh * DDIM * SDIM + s0;
    float2 accq[RED];
#pragma unroll
    for (int r = 0; r < RED; ++r) accq[r] = make_float2(0.f, 0.f);

    const int r8 = lane >> 3, seg = lane & 7;

#pragma unroll 2
    for (int g = 0; g < 16; ++g) {
#pragma unroll
        for (int j = 0; j < 8; ++j) {
            const int d = g * 8 + j;
            const float2 xv = *(const float2*)(xb + (size_t)d * SDIM);
            const float4 wa = *(const float4*)&wqt[d * 8];
            const float4 wb = *(const float4*)&wqt[d * 8 + 4];
            accq[0].x += xv.x * wa.x; accq[0].y += xv.y * wa.x;
            accq[1].x += xv.x * wa.y; accq[1].y += xv.y * wa.y;
            accq[2].x += xv.x * wa.z; accq[2].y += xv.y * wa.z;
            accq[3].x += xv.x * wa.w; accq[3].y += xv.y * wa.w;
            accq[4].x += xv.x * wb.x; accq[4].y += xv.y * wb.x;
            accq[5].x += xv.x * wb.y; accq[5].y += xv.y * wb.y;
            accq[6].x += xv.x * wb.z; accq[6].y += xv.y * wb.z;
            accq[7].x += xv.x * wb.w; accq[7].y += xv.y * wb.w;
            sxy[wave][j][lane] = xv.x + xv.y;
        }
        float ps = 0.f;
#pragma unroll
        for (int j = 0; j < 8; ++j) ps += sxy[wave][r8][seg * 8 + j];
        fpart[wave][g][r8][seg] = ps;
    }
#pragma unroll
    for (int r = 0; r < RED; ++r)
        *(float2*)(ws + WS_QR + ((size_t)(bh * RED + r)) * SDIM + s0) = accq[r];
    __syncthreads();
    if (t < DDIM) {
        float a = 0.f;
#pragma unroll
        for (int w = 0; w < 4; ++w)
#pragma unroll
            for (int s2 = 0; s2 < 8; ++s2)
                a += fpart[w][t >> 3][t & 7][s2];
        ws[chunk * 8192 + bh * DDIM + t] = a;
    }
}

__global__ __launch_bounds__(256) void k_mid(
        const float* __restrict__ bq, const float* __restrict__ Wk,
        const float* __restrict__ bk, const float* __restrict__ Wv,
        const float* __restrict__ bv, float* __restrict__ ws) {
    const int bh = blockIdx.x;
    const int h = bh & 7;
    const int t = threadIdx.x;
    const int wave = t >> 6, lane = t & 63;

    __shared__ float avgs[DDIM], kk[RED], bqs[RED];
    __shared__ float smax[4], ssum[4];
    __shared__ float cc;

    if (t < DDIM) {
        float a = 0.f;
#pragma unroll
        for (int c = 0; c < 8; ++c) a += ws[c * 8192 + bh * DDIM + t];
        avgs[t] = a * (1.0f / SDIM);
    }
    __syncthreads();
    if (t < RED) {
        const float* wkr = Wk + (h * RED + t) * DDIM;
        float a = 0.f;
#pragma unroll 8
        for (int d = 0; d < DDIM; ++d) a += wkr[d] * avgs[d];
        kk[t] = a + bk[h * RED + t];
        bqs[t] = bq[h * RED + t];
    }
    if (t < DDIM) {
        const float* wvr = Wv + (h * DDIM + t) * DDIM;
        float a = 0.f;
#pragma unroll 8
        for (int d = 0; d < DDIM; ++d) a += wvr[d] * avgs[d];
        ws[WS_VV + bh * DDIM + t] = a + bv[h * DDIM + t];
    }
    __syncthreads();
    if (t == 0) {
        float a = 0.f;
#pragma unroll
        for (int r = 0; r < RED; ++r) a += bqs[r] * kk[r];
        cc = a;
    }
    __syncthreads();

    const float4* qr4 = (const float4*)(ws + WS_QR + (size_t)bh * RED * SDIM);
    float4 vals[4];
    float m = -1e30f;
#pragma unroll
    for (int p = 0; p < 4; ++p) {
        float4 a;
        a.x = cc; a.y = cc; a.z = cc; a.w = cc;
#pragma unroll
        for (int r = 0; r < RED; ++r) {
            const float4 q = qr4[r * 1024 + t + 256 * p];
            const float kr = kk[r];
            a.x += q.x * kr; a.y += q.y * kr; a.z += q.z * kr; a.w += q.w * kr;
        }
        vals[p] = a;
        m = fmaxf(m, fmaxf(fmaxf(a.x, a.y), fmaxf(a.z, a.w)));
    }
    m = wave_reduce_max(m);
    if (lane == 0) smax[wave] = m;
    __syncthreads();
    const float gm = fmaxf(fmaxf(smax[0], smax[1]), fmaxf(smax[2], smax[3]));
    float sum = 0.f;
#pragma unroll
    for (int p = 0; p < 4; ++p) {
        vals[p].x = expf(vals[p].x - gm);
        vals[p].y = expf(vals[p].y - gm);
        vals[p].z = expf(vals[p].z - gm);
        vals[p].w = expf(vals[p].w - gm);
        sum += vals[p].x + vals[p].y + vals[p].z + vals[p].w;
    }
    sum = wave_reduce_sum(sum);
    if (lane == 0) ssum[wave] = sum;
    __syncthreads();
    const float inv = 1.0f / (ssum[0] + ssum[1] + ssum[2] + ssum[3]);
    float4* att4 = (float4*)(ws + WS_ATT + (size_t)bh * SDIM);
#pragma unroll
    for (int p = 0; p < 4; ++p) {
        float4 o;
        o.x = vals[p].x * inv; o.y = vals[p].y * inv;
        o.z = vals[p].z * inv; o.w = vals[p].w * inv;
        att4[t + 256 * p] = o;
    }
}

__global__ __launch_bounds__(256) void k_bcast(const float* __restrict__ ws,
                                               float* __restrict__ out) {
    const vfloat4* attn = (const vfloat4*)(ws + WS_ATT);
    const float* vv = ws + WS_VV;
    const size_t total = (size_t)BATCH * CH * (SDIM / 4);
    const size_t stride = (size_t)gridDim.x * blockDim.x;
    for (size_t f = (size_t)blockIdx.x * blockDim.x + threadIdx.x; f < total; f += stride) {
        const int s4 = (int)(f & 1023);
        const int ce = (int)((f >> 10) & 1023);
        const int b = (int)(f >> 20);
        const int bh = (b << 3) | (ce >> 7);
        const int e = ce & 127;
        const vfloat4 a = attn[bh * 1024 + s4];
        const float vx = vv[bh * 128 + e];
        vfloat4 o = a * vx;
        __builtin_nontemporal_store(o, ((vfloat4*)out) + f);
    }
}

extern "C" void kernel_launch(void* const* d_in, const int* in_sizes, int n_in,
                              void* d_out, int out_size, void* d_ws, size_t ws_size,
                              hipStream_t stream) {
    const float* x  = (const float*)d_in[0];
    const float* Wq = (const float*)d_in[1];
    const float* bq = (const float*)d_in[2];
    const float* Wk = (const float*)d_in[3];
    const float* bk = (const float*)d_in[4];
    const float* Wv = (const float*)d_in[5];
    const float* bv = (const float*)d_in[6];
    float* out = (float*)d_out;
    float* ws  = (float*)d_ws;

    void* args[] = {(void*)&x, (void*)&Wq, (void*)&bq, (void*)&Wk, (void*)&bk,
                    (void*)&Wv, (void*)&bv, (void*)&ws, (void*)&out};
    hipError_t err = hipLaunchCooperativeKernel((const void*)k_fused, dim3(512),
                                                dim3(256), args, 0, stream);
    if (err != hipSuccess) {
        // non-cooperative fallback: same math, qr staged through workspace
        k_pass1<<<512, 256, 0, stream>>>(x, Wq, ws);
        k_mid<<<BH, 256, 0, stream>>>(bq, Wk, bk, Wv, bv, ws);
        k_bcast<<<8192, 256, 0, stream>>>(ws, out);
    }
}

// Round 3
// 276.321 us; speedup vs baseline: 1.5494x; 1.4827x over previous
//
#include <hip/hip_runtime.h>
#include <math.h>

// Problem constants (MultiHeadCRA): B=8, C=1024, H=W=64
#define SDIM 4096      // spatial S = H*W
#define DDIM 128       // head_dim
#define RED 8          // reduced dim
#define BATCH 8
#define BH 64          // BATCH*HEADS
#define CH 1024        // channels per batch = HEADS*DDIM

// native 16B vector for nontemporal builtins
typedef float vfloat4 __attribute__((ext_vector_type(4)));

// workspace layout (floats):
//   avg partials [4 chunks][8192 rows]   @ 0        (32768)
//   v            [BH*128]                @ 32768
//   attn         [BH*4096]               @ 40960
//   qr partials  [4 dg][BH*8][4096]      @ 303104   (8.4M floats)
#define WS_AVG  0
#define WS_VV   32768
#define WS_ATT  40960
#define WS_QRP  303104
#define QRP_DG  2097152   // floats per dg plane = 64*8*4096

__inline__ __device__ float wave_reduce_sum(float v) {
#pragma unroll
    for (int o = 32; o > 0; o >>= 1) v += __shfl_down(v, o, 64);
    return v;
}
__inline__ __device__ float wave_reduce_max(float v) {
#pragma unroll
    for (int o = 32; o > 0; o >>= 1) v = fmaxf(v, __shfl_down(v, o, 64));
    return v;
}

// ---------------------------------------------------------------------------
// K1: single pass over x. Grid: 64 bh x 4 s-chunks(1024 col) x 4 d-groups(32 d)
//   = 1024 blocks (4/CU), 256 thr, float4 per lane (1KB/wave loads).
// Per thread: 8 q-projection partial accumulators (registers) -> qr partials.
// Avg row-sums via wave-local LDS transpose (no shuffles, no barriers in loop).
// ---------------------------------------------------------------------------
__global__ __launch_bounds__(256, 4) void k_qr(
        const float* __restrict__ x, const float* __restrict__ Wq,
        float* __restrict__ ws) {
    const int blk = blockIdx.x;
    const int dg = blk & 3, chunk = (blk >> 2) & 3, bh = blk >> 4;
    const int h = bh & 7;
    const int t = threadIdx.x;
    const int wave = t >> 6, lane = t & 63;
    const int r8 = lane >> 3, seg = lane & 7;

    __shared__ float wqt[32 * 8];          // Wq slice transposed: [d_local][r]
    __shared__ float sxy[4][8][65];        // per-wave column-sum staging (pad 65)
    __shared__ float fpart[4][4][8][9];    // [wave][group][row][seg] (pad 9)

    // stage Wq: t = dl*8 + r  (256 threads cover 32x8 exactly)
    wqt[t] = Wq[(h * RED + (t & 7)) * DDIM + dg * 32 + (t >> 3)];
    __syncthreads();

    const int s0 = chunk * 1024 + t * 4;
    const float* xb = x + (size_t)(bh * DDIM + dg * 32) * SDIM + s0;
    vfloat4 accq[RED];
#pragma unroll
    for (int r = 0; r < RED; ++r) accq[r] = (vfloat4)0.f;

#pragma unroll
    for (int g = 0; g < 4; ++g) {
#pragma unroll
        for (int j = 0; j < 8; ++j) {
            const int dl = g * 8 + j;
            const vfloat4 xv = *(const vfloat4*)(xb + (size_t)dl * SDIM);
            const float4 wa = *(const float4*)&wqt[dl * 8];
            const float4 wb = *(const float4*)&wqt[dl * 8 + 4];
            accq[0] += xv * wa.x;
            accq[1] += xv * wa.y;
            accq[2] += xv * wa.z;
            accq[3] += xv * wa.w;
            accq[4] += xv * wb.x;
            accq[5] += xv * wb.y;
            accq[6] += xv * wb.z;
            accq[7] += xv * wb.w;
            sxy[wave][j][lane] = xv[0] + xv[1] + xv[2] + xv[3];
        }
        // wave-local transpose-reduce (same-wave LDS order via lgkmcnt, no barrier)
        float ps = 0.f;
#pragma unroll
        for (int j = 0; j < 8; ++j) ps += sxy[wave][r8][seg * 8 + j];
        fpart[wave][g][r8][seg] = ps;
    }

    // qr partial store: per r, 1KB/wave contiguous
    float* qb = ws + WS_QRP + (size_t)dg * QRP_DG + (size_t)(bh * RED) * SDIM + s0;
#pragma unroll
    for (int r = 0; r < RED; ++r)
        *(vfloat4*)(qb + (size_t)r * SDIM) = accq[r];

    __syncthreads();
    if (t < 32) {
        // d_local = t; fold 4 waves x 8 segments
        const int g = t >> 3, rr = t & 7;
        float a = 0.f;
#pragma unroll
        for (int w = 0; w < 4; ++w)
#pragma unroll
            for (int s2 = 0; s2 < 8; ++s2)
                a += fpart[w][g][rr][s2];
        ws[WS_AVG + chunk * 8192 + bh * DDIM + dg * 32 + t] = a;
    }
}

// ---------------------------------------------------------------------------
// K2: per-(b,h) head math + scores + full softmax. 64 blocks x 256 thr.
// ---------------------------------------------------------------------------
__global__ __launch_bounds__(256) void k_head(
        const float* __restrict__ bq, const float* __restrict__ Wk,
        const float* __restrict__ bk, const float* __restrict__ Wv,
        const float* __restrict__ bv, float* __restrict__ ws) {
    const int bh = blockIdx.x;
    const int h = bh & 7;
    const int t = threadIdx.x;
    const int wave = t >> 6, lane = t & 63;

    __shared__ float avgs[DDIM], kk[RED], bqs[RED];
    __shared__ float smax[4], ssum[4];
    __shared__ float cc;

    if (t < DDIM) {
        float a = 0.f;
#pragma unroll
        for (int c = 0; c < 4; ++c) a += ws[WS_AVG + c * 8192 + bh * DDIM + t];
        avgs[t] = a * (1.0f / SDIM);
    }
    __syncthreads();
    if (t < RED) {
        const float* wkr = Wk + (h * RED + t) * DDIM;
        float a = 0.f;
#pragma unroll 8
        for (int d = 0; d < DDIM; ++d) a += wkr[d] * avgs[d];
        kk[t] = a + bk[h * RED + t];
        bqs[t] = bq[h * RED + t];
    }
    if (t < DDIM) {
        const float* wvr = Wv + (h * DDIM + t) * DDIM;
        float a = 0.f;
#pragma unroll 8
        for (int d = 0; d < DDIM; ++d) a += wvr[d] * avgs[d];
        ws[WS_VV + bh * DDIM + t] = a + bv[h * DDIM + t];
    }
    __syncthreads();
    if (t == 0) {
        float a = 0.f;
#pragma unroll
        for (int r = 0; r < RED; ++r) a += bqs[r] * kk[r];
        cc = a;
    }
    __syncthreads();

    // scores: fold 4 dg planes of qr partials, dot with k
    float4 vals[4];
    float m = -1e30f;
#pragma unroll
    for (int p = 0; p < 4; ++p) {
        float4 a;
        a.x = cc; a.y = cc; a.z = cc; a.w = cc;
#pragma unroll
        for (int r = 0; r < RED; ++r) {
            const size_t base = WS_QRP + (size_t)(bh * RED + r) * SDIM + (t + 256 * p) * 4;
            float4 q0 = *(const float4*)(ws + base);
            float4 q1 = *(const float4*)(ws + base + QRP_DG);
            float4 q2 = *(const float4*)(ws + base + 2 * (size_t)QRP_DG);
            float4 q3 = *(const float4*)(ws + base + 3 * (size_t)QRP_DG);
            const float kr = kk[r];
            a.x += (q0.x + q1.x + q2.x + q3.x) * kr;
            a.y += (q0.y + q1.y + q2.y + q3.y) * kr;
            a.z += (q0.z + q1.z + q2.z + q3.z) * kr;
            a.w += (q0.w + q1.w + q2.w + q3.w) * kr;
        }
        vals[p] = a;
        m = fmaxf(m, fmaxf(fmaxf(a.x, a.y), fmaxf(a.z, a.w)));
    }
    m = wave_reduce_max(m);
    if (lane == 0) smax[wave] = m;
    __syncthreads();
    const float gm = fmaxf(fmaxf(smax[0], smax[1]), fmaxf(smax[2], smax[3]));
    float sum = 0.f;
#pragma unroll
    for (int p = 0; p < 4; ++p) {
        vals[p].x = expf(vals[p].x - gm);
        vals[p].y = expf(vals[p].y - gm);
        vals[p].z = expf(vals[p].z - gm);
        vals[p].w = expf(vals[p].w - gm);
        sum += vals[p].x + vals[p].y + vals[p].z + vals[p].w;
    }
    sum = wave_reduce_sum(sum);
    if (lane == 0) ssum[wave] = sum;
    __syncthreads();
    const float inv = 1.0f / (ssum[0] + ssum[1] + ssum[2] + ssum[3]);
    float4* att4 = (float4*)(ws + WS_ATT + (size_t)bh * SDIM);
#pragma unroll
    for (int p = 0; p < 4; ++p) {
        float4 o;
        o.x = vals[p].x * inv; o.y = vals[p].y * inv;
        o.z = vals[p].z * inv; o.w = vals[p].w * inv;
        att4[t + 256 * p] = o;
    }
}

// ---------------------------------------------------------------------------
// K3: broadcast writer. Grid: 64 bh x 16 s-chunks(256 col) = 1024 blocks.
// Lane holds one attn vfloat4; wave = e-group; 32 nontemporal 1KB/wave stores.
// ---------------------------------------------------------------------------
__global__ __launch_bounds__(256) void k_wr(const float* __restrict__ ws,
                                            float* __restrict__ out) {
    const int blk = blockIdx.x;
    const int bh = blk >> 4, chunk = blk & 15;
    const int t = threadIdx.x;
    const int wave = t >> 6, lane = t & 63;

    __shared__ float vvs[DDIM];
    if (t < DDIM) vvs[t] = ws[WS_VV + bh * DDIM + t];

    const vfloat4 a4 =
        ((const vfloat4*)(ws + WS_ATT))[bh * 1024 + chunk * 64 + lane];
    __syncthreads();

    vfloat4* ob = (vfloat4*)out + (size_t)(bh * DDIM) * 1024 + chunk * 64 + lane;
#pragma unroll
    for (int i = 0; i < 32; ++i) {
        const int e = wave * 32 + i;
        vfloat4 o = a4 * vvs[e];
        __builtin_nontemporal_store(o, ob + (size_t)e * 1024);
    }
}

extern "C" void kernel_launch(void* const* d_in, const int* in_sizes, int n_in,
                              void* d_out, int out_size, void* d_ws, size_t ws_size,
                              hipStream_t stream) {
    const float* x  = (const float*)d_in[0];
    const float* Wq = (const float*)d_in[1];
    const float* bq = (const float*)d_in[2];
    const float* Wk = (const float*)d_in[3];
    const float* bk = (const float*)d_in[4];
    const float* Wv = (const float*)d_in[5];
    const float* bv = (const float*)d_in[6];
    float* out = (float*)d_out;
    float* ws  = (float*)d_ws;

    k_qr<<<1024, 256, 0, stream>>>(x, Wq, ws);
    k_head<<<BH, 256, 0, stream>>>(bq, Wk, bk, Wv, bv, ws);
    k_wr<<<1024, 256, 0, stream>>>(ws, out);
}